// Round 2
// baseline (367.750 us; speedup 1.0000x reference)
//
#include <hip/hip_runtime.h>

#define NB 32
#define NC 128
#define NH 56
#define NW 56
#define HP 58
#define WP 58
#define KK 1152
#define NPOS 3136                         // 56*56
#define XT_BYTES (NB * HP * WP * NC * 2)  // 27,557,888
#define AW_OFF XT_BYTES

typedef __attribute__((ext_vector_type(8))) short s16x8;
typedef __attribute__((ext_vector_type(4))) float f32x4;
typedef unsigned int u32;

__device__ __forceinline__ unsigned short f2bf(float f) {
    union { float f; unsigned int u; } v; v.f = f;
    unsigned int u = v.u + 0x7fffu + ((v.u >> 16) & 1u);
    return (unsigned short)(u >> 16);
}

__device__ __forceinline__ void gld16(const void* g, void* l) {
    __builtin_amdgcn_global_load_lds(
        (const __attribute__((address_space(1))) u32*)g,
        (__attribute__((address_space(3))) u32*)l, 16, 0, 0);
}

// ---- fused prologue (round-0 v1, measured-better; not the lever) ----
// blocks [0,1792) transpose x; [1792,4096) permute w.
__global__ void k_pro(const float* __restrict__ x, const float* __restrict__ w,
                      unsigned short* __restrict__ xt, unsigned short* __restrict__ aw) {
    int blk = blockIdx.x;
    int tid = threadIdx.x;
    if (blk >= 1792) {
        int idx = (blk - 1792) * 256 + tid;   // 589824 total
        if (idx < 512 * KK) {
            int j = idx & 7, lane = (idx >> 3) & 63, mt = (idx >> 9) & 31, s = idx >> 14;
            int m = mt * 16 + (lane & 15);
            int kg = s * 32 + (lane >> 4) * 8 + j;
            int g = kg >> 7, ic = kg & 127;
            aw[idx] = f2bf(w[(m * 128 + ic) * 9 + g]);
        }
        return;
    }
    __shared__ unsigned short tile[128 * 57];
    int b = blk / NH, y = blk % NH;
    const float* xb = x + (size_t)b * (NC * NPOS) + y * NW;
#pragma unroll
    for (int p = 0; p < 7; ++p) {
        int idx = p * 256 + tid;            // 1792 float4 = 7168 floats
        int c = idx / 14, i = idx - c * 14;
        float4 v = *(const float4*)(xb + c * NPOS + i * 4);
        unsigned short* tp = &tile[c * 57 + i * 4];
        tp[0] = f2bf(v.x); tp[1] = f2bf(v.y); tp[2] = f2bf(v.z); tp[3] = f2bf(v.w);
    }
    __syncthreads();
    unsigned short* xrow = xt + ((size_t)(b * HP + y + 1) * WP + 1) * NC;
#pragma unroll
    for (int p = 0; p < 4; ++p) {
        int idx = p * 256 + tid;            // 896 = 56 x-pos * 16 chunks
        if (idx < 896) {
            int xp = idx >> 4, cgi = idx & 15;
            s16x8 v8;
#pragma unroll
            for (int j = 0; j < 8; ++j)
                v8[j] = (short)tile[(cgi * 8 + j) * 57 + xp];
            *(s16x8*)(xrow + xp * NC + cgi * 8) = v8;
        }
    }
    if (tid < 128) {
        xt[((size_t)(b * HP + y + 1) * WP + 0) * NC + tid] = 0;
        xt[((size_t)(b * HP + y + 1) * WP + 57) * NC + tid] = 0;
    }
    if (y == 0) {
        unsigned short* r0 = xt + (size_t)(b * HP + 0) * WP * NC;
        for (int i = tid; i < WP * NC; i += 256) r0[i] = 0;
    }
    if (y == 55) {
        unsigned short* r57 = xt + (size_t)(b * HP + 57) * WP * NC;
        for (int i = tid; i < WP * NC; i += 256) r57[i] = 0;
    }
}

// ---- main v2: counted-vmcnt pipeline (T3/T4) + setprio (T5) ----
// 8 waves, M=512 (4 ranks x 128 ch), N=112 (2 image rows), K=1152.
// 9 stages of K=128 (one 3x3 tap each). Per stage each wave issues 16 A-loads
// (stage-granular reg ping-pong, compile-time bank index) THEN 4 gld16 for
// st+1, waits vmcnt(20) (st's 20 loads done, st+1's 20 stay in flight across
// both raw s_barriers and the MFMA phase), never vmcnt(0) in the main loop.
// A-loads precede gld16 in issue order so the compiler's own A-waits can
// never force the B-prefetch to drain (vmcnt waits are ordered).
__global__ void __launch_bounds__(512, 2) k_main(
    const unsigned short* __restrict__ xt, const unsigned short* __restrict__ aw,
    const float* __restrict__ cwr, const float* __restrict__ cwc,
    const float* __restrict__ brow, const float* __restrict__ bcol,
    const float* __restrict__ bch, float* __restrict__ out) {
    __shared__ __align__(16) unsigned char ldsB[2][28672];   // 112 rows x 256B

    const int tid = threadIdx.x;
    const int lane = tid & 63;
    const int wv = tid >> 6;
    const int l15 = lane & 15, quad = lane >> 4;
    const int ph = (wv & 1) * 2;            // per-parity sub-slice rotation
    const int blk = blockIdx.x;
    const int b = blk / 28;
    const int tile0 = (blk - b * 28) * 112;

    const unsigned char* xt_b = (const unsigned char*)xt + (size_t)b * (HP * WP * NC * 2);
    const unsigned char* gA = (const unsigned char*)aw + wv * 1024 + lane * 16;

    // B staging: wave wv (0..6) stages rows wv*16..+15; gld16 #h covers 4 rows
    // (h*4 + lane>>4), phys chunk lane&15, global chunk (lane&15)^(row&15).
    const unsigned char* gB[4];
    if (wv < 7) {
#pragma unroll
        for (int h = 0; h < 4; ++h) {
            int rl = h * 4 + (lane >> 4);
            int row = wv * 16 + rl;
            int pos = tile0 + row;
            int yy = pos / 56, xx = pos - yy * 56;
            int c = (lane & 15) ^ rl;
            gB[h] = xt_b + ((yy + 1) * WP + (xx + 1)) * (NC * 2) + c * 16;
        }
    }

    s16x8 A[2][4][4];          // [bank][beat-slot][rank]; slot j holds slice st*4+((j+ph)&3)
    f32x4 acc[4][7] = {};      // [rank][ntile]

    auto aloadAll = [&](int st, int bk) {
#pragma unroll
        for (int i = 0; i < 4; ++i) {
            int s32 = st * 4 + ((i + ph) & 3);
#pragma unroll
            for (int r = 0; r < 4; ++r)
                A[bk][i][r] = *(const s16x8*)(gA + s32 * 32768 + r * 8192);
        }
    };
    auto bissue = [&](int st, int buf) {
        if (wv < 7) {
            int dy = (st * 11) >> 5, dx = st - dy * 3;
            int off = ((dy - 1) * WP + (dx - 1)) * (NC * 2);
            unsigned char* L = &ldsB[buf][wv * 4096];
#pragma unroll
            for (int h = 0; h < 4; ++h) gld16(gB[h] + off, L + h * 1024);
        }
    };

// One K=128 stage. CUR/LAST are compile-time literals (A-bank + LDS-buf
// indices must be static). Two raw barriers, no vmcnt(0) except final stage.
#define STAGE(ST, CUR, LAST)                                                  \
    {                                                                         \
        if (!(LAST)) { aloadAll((ST) + 1, (CUR) ^ 1); bissue((ST) + 1, (CUR) ^ 1); } \
        if (LAST) { asm volatile("s_waitcnt vmcnt(0)" ::: "memory"); }        \
        else      { asm volatile("s_waitcnt vmcnt(20)" ::: "memory"); }       \
        __builtin_amdgcn_s_barrier();                                         \
        const unsigned char* Lb = &ldsB[CUR][0];                              \
        _Pragma("unroll")                                                     \
        for (int j = 0; j < 4; ++j) {                                         \
            const int kkw = (j + ph) & 3;                                     \
            s16x8 bf[7];                                                      \
            _Pragma("unroll")                                                 \
            for (int t = 0; t < 7; ++t)                                       \
                bf[t] = *(const s16x8*)(Lb + (t * 16 + l15) * 256             \
                                           + (((kkw * 4 + quad) ^ l15) << 4)); \
            __builtin_amdgcn_s_setprio(1);                                    \
            _Pragma("unroll")                                                 \
            for (int r = 0; r < 4; ++r)                                       \
                _Pragma("unroll")                                             \
                for (int t = 0; t < 7; ++t)                                   \
                    acc[r][t] = __builtin_amdgcn_mfma_f32_16x16x32_bf16(      \
                        A[CUR][j][r], bf[t], acc[r][t], 0, 0, 0);             \
            __builtin_amdgcn_s_setprio(0);                                    \
        }                                                                     \
        if (!(LAST)) __builtin_amdgcn_s_barrier();                            \
    }

    aloadAll(0, 0);
    bissue(0, 0);
    for (int st2 = 0; st2 < 4; ++st2) {     // stages 0..7, banks alternate 0/1
        STAGE(st2 * 2, 0, 0)
        STAGE(st2 * 2 + 1, 1, 0)
    }
    STAGE(8, 0, 1)                          // 8&1==0: bank/buf 0
#undef STAGE

    // epilogue: inline softmax over rank + combine + biases, fp32 store
#pragma unroll
    for (int t = 0; t < 7; ++t) {
        int pos = tile0 + t * 16 + l15;
        int yy = pos / 56, xx = pos - yy * 56;
        float v0 = cwr[yy]       + cwc[xx];
        float v1 = cwr[56 + yy]  + cwc[56 + xx];
        float v2 = cwr[112 + yy] + cwc[112 + xx];
        float v3 = cwr[168 + yy] + cwc[168 + xx];
        float mx = fmaxf(fmaxf(v0, v1), fmaxf(v2, v3));
        float e0 = __expf(v0 - mx), e1 = __expf(v1 - mx);
        float e2 = __expf(v2 - mx), e3 = __expf(v3 - mx);
        float inv = 1.0f / (e0 + e1 + e2 + e3);
        float c0 = e0 * inv, c1 = e1 * inv, c2 = e2 * inv, c3 = e3 * inv;
        float rb = brow[yy] + bcol[xx];
#pragma unroll
        for (int r = 0; r < 4; ++r) {
            int ch = wv * 16 + quad * 4 + r;
            float v = acc[0][t][r] * c0 + acc[1][t][r] * c1
                    + acc[2][t][r] * c2 + acc[3][t][r] * c3;
            out[((size_t)b * NC + ch) * NPOS + pos] = v + bch[ch] + rb;
        }
    }
}

extern "C" void kernel_launch(void* const* d_in, const int* in_sizes, int n_in,
                              void* d_out, int out_size, void* d_ws, size_t ws_size,
                              hipStream_t stream) {
    const float* x    = (const float*)d_in[0];
    const float* w    = (const float*)d_in[1];
    const float* cwr  = (const float*)d_in[2];
    const float* cwc  = (const float*)d_in[3];
    const float* brow = (const float*)d_in[4];
    const float* bcol = (const float*)d_in[5];
    const float* bch  = (const float*)d_in[6];
    float* out = (float*)d_out;

    unsigned char* ws = (unsigned char*)d_ws;
    unsigned short* xt = (unsigned short*)ws;
    unsigned short* aw = (unsigned short*)(ws + AW_OFF);

    k_pro<<<4096, 256, 0, stream>>>(x, w, xt, aw);   // xpose + wconv fused
    k_main<<<NB * 28, 512, 0, stream>>>(xt, aw, cwr, cwc, brow, bcol, bch, out);
}

// Round 3
// 236.904 us; speedup vs baseline: 1.5523x; 1.5523x over previous
//
#include <hip/hip_runtime.h>

#define NB 32
#define NC 128
#define NH 56
#define NW 56
#define HP 58
#define WP 58
#define KK 1152
#define NPOS 3136                         // 56*56
#define XT_BYTES (NB * HP * WP * NC * 2)  // 27,557,888
#define AW_OFF XT_BYTES

typedef __attribute__((ext_vector_type(8))) short s16x8;
typedef __attribute__((ext_vector_type(4))) float f32x4;
typedef unsigned int u32;

__device__ __forceinline__ unsigned short f2bf(float f) {
    union { float f; unsigned int u; } v; v.f = f;
    unsigned int u = v.u + 0x7fffu + ((v.u >> 16) & 1u);
    return (unsigned short)(u >> 16);
}

__device__ __forceinline__ void gld16(const void* g, void* l) {
    __builtin_amdgcn_global_load_lds(
        (const __attribute__((address_space(1))) u32*)g,
        (__attribute__((address_space(3))) u32*)l, 16, 0, 0);
}

// ---- fused prologue (v1, proven) ----
// blocks [0,1792) transpose x; [1792,4096) permute w.
__global__ void k_pro(const float* __restrict__ x, const float* __restrict__ w,
                      unsigned short* __restrict__ xt, unsigned short* __restrict__ aw) {
    int blk = blockIdx.x;
    int tid = threadIdx.x;
    if (blk >= 1792) {
        int idx = (blk - 1792) * 256 + tid;   // 589824 total
        if (idx < 512 * KK) {
            int j = idx & 7, lane = (idx >> 3) & 63, mt = (idx >> 9) & 31, s = idx >> 14;
            int m = mt * 16 + (lane & 15);
            int kg = s * 32 + (lane >> 4) * 8 + j;
            int g = kg >> 7, ic = kg & 127;
            aw[idx] = f2bf(w[(m * 128 + ic) * 9 + g]);
        }
        return;
    }
    __shared__ unsigned short tile[128 * 57];
    int b = blk / NH, y = blk % NH;
    const float* xb = x + (size_t)b * (NC * NPOS) + y * NW;
#pragma unroll
    for (int p = 0; p < 7; ++p) {
        int idx = p * 256 + tid;            // 1792 float4 = 7168 floats
        int c = idx / 14, i = idx - c * 14;
        float4 v = *(const float4*)(xb + c * NPOS + i * 4);
        unsigned short* tp = &tile[c * 57 + i * 4];
        tp[0] = f2bf(v.x); tp[1] = f2bf(v.y); tp[2] = f2bf(v.z); tp[3] = f2bf(v.w);
    }
    __syncthreads();
    unsigned short* xrow = xt + ((size_t)(b * HP + y + 1) * WP + 1) * NC;
#pragma unroll
    for (int p = 0; p < 4; ++p) {
        int idx = p * 256 + tid;            // 896 = 56 x-pos * 16 chunks
        if (idx < 896) {
            int xp = idx >> 4, cgi = idx & 15;
            s16x8 v8;
#pragma unroll
            for (int j = 0; j < 8; ++j)
                v8[j] = (short)tile[(cgi * 8 + j) * 57 + xp];
            *(s16x8*)(xrow + xp * NC + cgi * 8) = v8;
        }
    }
    if (tid < 128) {
        xt[((size_t)(b * HP + y + 1) * WP + 0) * NC + tid] = 0;
        xt[((size_t)(b * HP + y + 1) * WP + 57) * NC + tid] = 0;
    }
    if (y == 0) {
        unsigned short* r0 = xt + (size_t)(b * HP + 0) * WP * NC;
        for (int i = tid; i < WP * NC; i += 256) r0[i] = 0;
    }
    if (y == 55) {
        unsigned short* r57 = xt + (size_t)(b * HP + 57) * WP * NC;
        for (int i = tid; i < WP * NC; i += 256) r57[i] = 0;
    }
}

// ---- main v3: 4-wave blocks, 2 independent blocks/CU ----
// Per-wave work is IDENTICAL to the proven 132us kernel (4 ranks x 16 ch x
// 112 pos, beat-granular A ping-pong, 28 MFMA/beat, __syncthreads/stage).
// Change: block = 4 waves covering ONE 64-channel half (h = blk&1 of a pair),
// so regs (8 x 240 = 1920) and LDS (2 x 57KB = 114KB) fit TWO independent
// blocks per CU. Wave->SIMD round-robin puts one wave of EACH block on every
// SIMD; blocks never inter-sync, so they drift anti-phase and one block's
// MFMA bursts fill the other's barrier/load stalls (lockstep contention was
// the measured 47%-pipe ceiling). B tile staged by 4 waves -> 7 gld16/wave.
__global__ void __launch_bounds__(256, 2) k_main(
    const unsigned short* __restrict__ xt, const unsigned short* __restrict__ aw,
    const float* __restrict__ cwr, const float* __restrict__ cwc,
    const float* __restrict__ brow, const float* __restrict__ bcol,
    const float* __restrict__ bch, float* __restrict__ out) {
    __shared__ __align__(16) unsigned char ldsB[2][28672];   // 112 rows x 256B

    const int tid = threadIdx.x;
    const int lane = tid & 63;
    const int wv = tid >> 6;                // 0..3
    const int l15 = lane & 15, quad = lane >> 4;
    const int ph = (wv & 1) * 2;            // per-parity sub-slice rotation
    const int blk = blockIdx.x;
    const int b = blk / 56;
    const int rem = blk - b * 56;
    const int pt = rem >> 1;                // position tile [0,28)
    const int h = rem & 1;                  // channel half [0,2)
    const int tile0 = pt * 112;

    const unsigned char* xt_b = (const unsigned char*)xt + (size_t)b * (HP * WP * NC * 2);
    // A fragment rows: m = r*128 + h*64 + wv*16 + l15  ->  mt = 8r + 4h + wv
    const unsigned char* gA = (const unsigned char*)aw + (h * 4 + wv) * 1024 + lane * 16;

    // B staging: wave wv stages rows wv*28..wv*28+27 via 7 gld16 (4 rows each:
    // row = wv*28 + g*4 + lane>>4, phys chunk lane&15, global chunk ^(row&15)).
    const unsigned char* gB[7];
#pragma unroll
    for (int g = 0; g < 7; ++g) {
        int row = wv * 28 + g * 4 + (lane >> 4);
        int pos = tile0 + row;
        int yy = pos / 56, xx = pos - yy * 56;
        int c = (lane & 15) ^ (row & 15);
        gB[g] = xt_b + ((yy + 1) * WP + (xx + 1)) * (NC * 2) + c * 16;
    }

    s16x8 Areg[2][4];          // [pingpong][rank]
    f32x4 acc[4][7] = {};      // [rank][ntile]

    auto aload = [&](int s32, int pp) {
#pragma unroll
        for (int r = 0; r < 4; ++r)
            Areg[pp][r] = *(const s16x8*)(gA + s32 * 32768 + r * 8192);
    };
    auto bissue = [&](int st, int buf) {
        int dy = (st * 11) >> 5, dx = st - dy * 3;
        int off = ((dy - 1) * WP + (dx - 1)) * (NC * 2);
        unsigned char* L = &ldsB[buf][wv * 7168];
#pragma unroll
        for (int g = 0; g < 7; ++g) gld16(gB[g] + off, L + g * 1024);
    };

    aload(ph, 0);              // first slice in this wave's rotated sequence
    bissue(0, 0);
    __syncthreads();

    for (int st = 0; st < 9; ++st) {
        const int cur = st & 1;
        if (st < 8) bissue(st + 1, cur ^ 1);
        const unsigned char* L = &ldsB[cur][0];
#pragma unroll
        for (int j = 0; j < 4; ++j) {
            const int kkw = (j + ph) & 3;      // this wave's sub-slice this beat
            // prefetch next slice in this wave's own sequence
            if (!(st == 8 && j == 3)) {
                int nslice = (j < 3) ? st * 4 + (((j + 1) + ph) & 3)
                                     : (st + 1) * 4 + ph;
                aload(nslice, (j + 1) & 1);
            }
            s16x8 bf[7];
#pragma unroll
            for (int t = 0; t < 7; ++t)
                bf[t] = *(const s16x8*)(L + (t * 16 + l15) * 256
                                          + (((kkw * 4 + quad) ^ l15) << 4));
#pragma unroll
            for (int r = 0; r < 4; ++r)
#pragma unroll
                for (int t = 0; t < 7; ++t)
                    acc[r][t] = __builtin_amdgcn_mfma_f32_16x16x32_bf16(
                        Areg[j & 1][r], bf[t], acc[r][t], 0, 0, 0);
        }
        __syncthreads();
    }

    // epilogue: inline softmax over rank + combine + biases, fp32 store
#pragma unroll
    for (int t = 0; t < 7; ++t) {
        int pos = tile0 + t * 16 + l15;
        int yy = pos / 56, xx = pos - yy * 56;
        float v0 = cwr[yy]       + cwc[xx];
        float v1 = cwr[56 + yy]  + cwc[56 + xx];
        float v2 = cwr[112 + yy] + cwc[112 + xx];
        float v3 = cwr[168 + yy] + cwc[168 + xx];
        float mx = fmaxf(fmaxf(v0, v1), fmaxf(v2, v3));
        float e0 = __expf(v0 - mx), e1 = __expf(v1 - mx);
        float e2 = __expf(v2 - mx), e3 = __expf(v3 - mx);
        float inv = 1.0f / (e0 + e1 + e2 + e3);
        float c0 = e0 * inv, c1 = e1 * inv, c2 = e2 * inv, c3 = e3 * inv;
        float rb = brow[yy] + bcol[xx];
#pragma unroll
        for (int r = 0; r < 4; ++r) {
            int ch = h * 64 + wv * 16 + quad * 4 + r;
            float v = acc[0][t][r] * c0 + acc[1][t][r] * c1
                    + acc[2][t][r] * c2 + acc[3][t][r] * c3;
            out[((size_t)b * NC + ch) * NPOS + pos] = v + bch[ch] + rb;
        }
    }
}

extern "C" void kernel_launch(void* const* d_in, const int* in_sizes, int n_in,
                              void* d_out, int out_size, void* d_ws, size_t ws_size,
                              hipStream_t stream) {
    const float* x    = (const float*)d_in[0];
    const float* w    = (const float*)d_in[1];
    const float* cwr  = (const float*)d_in[2];
    const float* cwc  = (const float*)d_in[3];
    const float* brow = (const float*)d_in[4];
    const float* bcol = (const float*)d_in[5];
    const float* bch  = (const float*)d_in[6];
    float* out = (float*)d_out;

    unsigned char* ws = (unsigned char*)d_ws;
    unsigned short* xt = (unsigned short*)ws;
    unsigned short* aw = (unsigned short*)(ws + AW_OFF);

    k_pro<<<4096, 256, 0, stream>>>(x, w, xt, aw);   // xpose + wconv fused
    k_main<<<NB * 56, 256, 0, stream>>>(xt, aw, cwr, cwc, brow, bcol, bch, out);
}